// Round 4
// baseline (102.038 us; speedup 1.0000x reference)
//
#include <hip/hip_runtime.h>
#include <hip/hip_bf16.h>
#include <cstdint>
#include <cstddef>

// ---------- types ----------
typedef __bf16 bf16x8 __attribute__((ext_vector_type(8)));
typedef float  f32x4  __attribute__((ext_vector_type(4)));

static constexpr int B  = 16;
static constexpr int T  = 4096;
static constexpr int D  = 256;
static constexpr int M  = B * T;          // 65536 rows
static constexpr int SEGS = 64;           // segments along T
static constexpr int SEGL = T / SEGS;     // 64 steps per segment

// ---------- build fragment-major interleaved bf16 weights ----------
// Wp_s element layout: [(ks*32 + fg)*64 + lane] * 8 bf16 elems, where
//   fg in 0..31, lane = kg*16 + rl, elem ko in [0,8)
//   stored value = W_{s,gate}[rc][ks*32 + kg*8 + ko]
// fg decomposition (16-wave config): w = fg>>1 (wave 0..15), gate = fg&1,
//   rc = w*16 + rl  (each lane owns ONE real col; frag pair = gate0/gate1)
__global__ void cvt_w(const float* __restrict__ W0, const float* __restrict__ W1,
                      const float* __restrict__ W2, const float* __restrict__ W3,
                      __bf16* __restrict__ wp) {
    int i = blockIdx.x * blockDim.x + threadIdx.x;   // 0..32767
    int s    = i >> 14;
    int r    = i & 16383;
    int ks   = r >> 11;          // 0..7
    int fg   = (r >> 6) & 31;    // 0..31
    int lane = r & 63;
    int kg = lane >> 4, rl = lane & 15;
    int w = fg >> 1, gate = fg & 1;
    int rc = w * 16 + rl;
    const float* src = (s == 0) ? (gate ? W1 : W0) : (gate ? W3 : W2);
    const float* p = src + (size_t)rc * 256 + ks * 32 + kg * 8;
    bf16x8 o;
#pragma unroll
    for (int j = 0; j < 8; ++j) o[j] = (__bf16)p[j];
    *reinterpret_cast<bf16x8*>(wp + (size_t)s * 131072 +
                               ((size_t)((ks * 32 + fg) * 64 + lane)) * 8) = o;
}

// ---------- fused two-stage gated-linear kernel + per-segment scan compose ----
// Block: 128 rows x 512 virtual cols (256 real) = 2 (batch, segment) pairs.
// 1024 threads / 16 waves; wave w owns real cols [w*16, w*16+16), 1 col/lane.
// Halves weight L2 traffic vs 64-row blocks (each block still reads full Wp).
// x staged f32->bf16 into LDS (full K=256, XOR-swizzled); W streamed from L2
// as per-lane-contiguous fragments, 2-deep pipelined; h gated in regs -> LDS
// (b16 scalar, swizzled); stage1 reads h from LDS; out -> ftile (f32, bank-
// swizzled col ^ (row&7)<<2) + regs, cheap barrier, global stores (no trailing
// barrier), then in-LDS per-segment (A,Mx) scan composition (2 segments).
__launch_bounds__(1024, 4)
__global__ void gln_fused(const float* __restrict__ x,
                          const __bf16* __restrict__ wp,
                          const float* __restrict__ b0, const float* __restrict__ b1,
                          const float* __restrict__ b2, const float* __restrict__ b3,
                          float* __restrict__ out,
                          float2* __restrict__ seg_am) {
    extern __shared__ char smem[];         // 131072 B dynamic
    char* xlds = smem;                     // [128][256] bf16, 16B-chunk XOR swizzle
    char* hlds = smem + 65536;             // [128][256] bf16, same swizzle
    float* ftile = reinterpret_cast<float*>(smem);  // [128][256] f32, overlays both

    const int tid  = threadIdx.x;          // 0..1023
    const int lane = tid & 63;
    const int wid  = tid >> 6;             // 0..15
    const int rl   = lane & 15;
    const int kg   = lane >> 4;            // 0..3
    const int row0 = blockIdx.x * 128;

    // per-wave weight base pointers (stage 0 / stage 1); fg = wid*2 + f
    const __bf16* wv0 = wp + ((size_t)(wid * 2) * 64 + lane) * 8;
    const __bf16* wv1 = wv0 + 131072;

    bf16x8 bbuf[2][2];
    auto loadB = [&](int p, const __bf16* wvb, int ks) {
#pragma unroll
        for (int f = 0; f < 2; ++f)
            bbuf[p][f] = *reinterpret_cast<const bf16x8*>(wvb + ks * 16384 + f * 512);
    };

    // ---- stage x rows [row0, row0+128) into LDS as bf16 ----
    {
        int r  = tid >> 3;         // 0..127
        int c0 = tid & 7;          // base 16B-chunk
        const float* xr = x + (size_t)(row0 + r) * 256;
        float4 xa[4][2];
#pragma unroll
        for (int ci = 0; ci < 4; ++ci) {
            const float4* p = reinterpret_cast<const float4*>(xr + (c0 + ci * 8) * 8);
            xa[ci][0] = p[0];
            xa[ci][1] = p[1];
        }
#pragma unroll
        for (int ci = 0; ci < 4; ++ci) {
            int ck = c0 + ci * 8;  // 0..31
            bf16x8 o = { (__bf16)xa[ci][0].x, (__bf16)xa[ci][0].y,
                         (__bf16)xa[ci][0].z, (__bf16)xa[ci][0].w,
                         (__bf16)xa[ci][1].x, (__bf16)xa[ci][1].y,
                         (__bf16)xa[ci][1].z, (__bf16)xa[ci][1].w };
            *reinterpret_cast<bf16x8*>(&xlds[r * 512 + ((ck ^ (r & 7)) * 16)]) = o;
        }
    }
    loadB(0, wv0, 0);              // stage-0 ks0 prefetch, hidden under x staging
    __syncthreads();

    f32x4 acc[8][2];

    // one GEMM stage: A from LDS (128 rows, K=256), B 2-deep pipelined from L2.
    // Assumes bbuf[0] holds this stage's ks=0 fragments on entry.
    auto run_stage = [&](const char* alds, const __bf16* wvb) {
#pragma unroll
        for (int m = 0; m < 8; ++m)
#pragma unroll
            for (int f = 0; f < 2; ++f) acc[m][f] = (f32x4){0.f, 0.f, 0.f, 0.f};
#pragma unroll
        for (int ks = 0; ks < 8; ++ks) {
            if (ks < 7) loadB((ks + 1) & 1, wvb, ks + 1);   // prefetch next ks
#pragma unroll
            for (int mh = 0; mh < 2; ++mh) {                // 4-row-tile chunks
                bf16x8 aR[4];
#pragma unroll
                for (int mi = 0; mi < 4; ++mi) {
                    int row = (mh * 4 + mi) * 16 + rl;
                    int ck  = (ks * 4 + kg) ^ (rl & 7);
                    aR[mi] = *reinterpret_cast<const bf16x8*>(&alds[row * 512 + ck * 16]);
                }
#pragma unroll
                for (int mi = 0; mi < 4; ++mi)
#pragma unroll
                    for (int f = 0; f < 2; ++f)
                        acc[mh * 4 + mi][f] = __builtin_amdgcn_mfma_f32_16x16x32_bf16(
                            aR[mi], bbuf[ks & 1][f], acc[mh * 4 + mi][f], 0, 0, 0);
            }
        }
    };

    const int rc = wid * 16 + rl;          // this lane's real output col

    // ---- stage 0: h = (x@W0^T+b0) * sigmoid(x@W1^T+b1), into hlds ----
    run_stage(xlds, wv0);
    loadB(0, wv1, 0);              // stage-1 ks0 prefetch, hidden under epilogue 0
    {
        float bb0 = b0[rc];
        float bb1 = b1[rc];
        int cb = rc * 2;                   // byte col
        int ck = cb >> 4;                  // 16B chunk
        int off = cb & 15;
#pragma unroll
        for (int m = 0; m < 8; ++m)
#pragma unroll
            for (int j = 0; j < 4; ++j) {
                int row = m * 16 + kg * 4 + j;
                float hv = (acc[m][0][j] + bb0) *
                           (1.0f / (1.0f + __expf(-(acc[m][1][j] + bb1))));
                *reinterpret_cast<__bf16*>(
                    &hlds[row * 512 + ((ck ^ (row & 7)) * 16) + off]) = (__bf16)hv;
            }
    }
    __syncthreads();

    // ---- stage 1: out = (h@W2^T+b2) * sigmoid(h@W3^T+b3) ----
    run_stage(hlds, wv1);
    __syncthreads();   // all hlds/xlds reads done before ftile overwrites them

    // epilogue-1 part A: gated values -> regs + LDS ftile (bank-swizzled)
    float ov[32];
    {
        float bb2 = b2[rc];
        float bb3 = b3[rc];
#pragma unroll
        for (int m = 0; m < 8; ++m)
#pragma unroll
            for (int j = 0; j < 4; ++j) {
                int row = m * 16 + kg * 4 + j;
                float v = (acc[m][0][j] + bb2) *
                          (1.0f / (1.0f + __expf(-(acc[m][1][j] + bb3))));
                ov[m * 4 + j] = v;
                int col = rc ^ ((row & 7) << 2);
                ftile[row * 256 + col] = v;
            }
    }
    __syncthreads();   // LDS-only drain (no vmem stores outstanding): cheap

    // epilogue-1 part B: global stores; NO trailing barrier -> drain overlaps
#pragma unroll
    for (int m = 0; m < 8; ++m)
#pragma unroll
        for (int j = 0; j < 4; ++j) {
            int row = m * 16 + kg * 4 + j;
            out[(size_t)(row0 + row) * 256 + rc] = ov[m * 4 + j];
        }

    // ---- fused scan_seg: 2 segments' (A, Mx) composition from LDS tile ----
    if (tid < 512) {
        int c     = tid & 255;
        int sidx  = tid >> 8;             // 0 or 1: which 64-row half
        int batch = row0 >> 12;           // row0 / T
        int t0    = (row0 & 4095) + sidx * 64;
        int seg   = t0 >> 6;
        int cc    = (c + t0) & 255;
        int rbase = sidx * 64;
        float A = 0.f, Mx = -1e30f;
#pragma unroll 8
        for (int i = 0; i < SEGL; ++i) {
            int row = rbase + i;
            int col = ((cc + i) & 255) ^ ((row & 7) << 2);
            float v = ftile[row * 256 + col];
            A += v;
            Mx = fmaxf(Mx + v, 0.f);
        }
        float2 o; o.x = A; o.y = Mx;
        seg_am[(size_t)(batch * SEGS + seg) * 256 + c] = o;
    }
}

// ---------- scan phase 2: sequential scan over segment boundaries ----------
__global__ void scan_bound(const float2* __restrict__ seg_am,
                           const float* __restrict__ hidden,
                           float* __restrict__ seg_state) {
    int tid   = blockIdx.x * blockDim.x + threadIdx.x;
    int c     = tid & 255;
    int batch = tid >> 8;
    float s = hidden[batch * 256 + ((c + 255) & 255)];
    for (int seg = 0; seg < SEGS; ++seg) {
        seg_state[(size_t)(batch * SEGS + seg) * 256 + c] = s;
        float2 am = seg_am[(size_t)(batch * SEGS + seg) * 256 + c];
        s = fmaxf(s + am.x, am.y);
    }
}

// ---------- scan phase 3: replay segment, write outputs in-place ----------
__global__ void scan_apply(float* __restrict__ bio,
                           const float* __restrict__ seg_state,
                           float* __restrict__ last) {
    int tid   = blockIdx.x * blockDim.x + threadIdx.x;
    int c     = tid & 255;
    int rest  = tid >> 8;
    int batch = rest & 15;
    int seg   = rest >> 4;
    float s = seg_state[(size_t)(batch * SEGS + seg) * 256 + c];
    float* base = bio + (size_t)batch * T * D;
    int t0 = seg * SEGL;
#pragma unroll 8
    for (int i = 0; i < SEGL; ++i) {
        int t = t0 + i;
        size_t idx = (size_t)t * 256 + ((c + t) & 255);
        float v = base[idx];
        s = fmaxf(s + v, 0.f);
        base[idx] = s;
    }
    if (seg == SEGS - 1) last[batch * 256 + ((c + 255) & 255)] = s;
}

// ---------- launch ----------
extern "C" void kernel_launch(void* const* d_in, const int* in_sizes, int n_in,
                              void* d_out, int out_size, void* d_ws, size_t ws_size,
                              hipStream_t stream) {
    const float* x      = (const float*)d_in[0];
    const float* hidden = (const float*)d_in[1];
    const float* W0 = (const float*)d_in[2];
    const float* b0 = (const float*)d_in[3];
    const float* W1 = (const float*)d_in[4];
    const float* b1 = (const float*)d_in[5];
    const float* W2 = (const float*)d_in[6];
    const float* b2 = (const float*)d_in[7];
    const float* W3 = (const float*)d_in[8];
    const float* b3 = (const float*)d_in[9];

    float* out  = (float*)d_out;
    float* last = out + (size_t)M * D;

    char* ws = (char*)d_ws;
    __bf16* wpb       = (__bf16*)ws;                     // 524,288 B (Wp0, Wp1)
    float2* seg_am    = (float2*)(ws + 524288);          // 2,097,152 B
    float*  seg_state = (float*)(ws + 524288 + 2097152); // 1,048,576 B

    static bool attr_done = false;
    if (!attr_done) {
        hipFuncSetAttribute(reinterpret_cast<const void*>(&gln_fused),
                            hipFuncAttributeMaxDynamicSharedMemorySize, 131072);
        attr_done = true;
    }

    cvt_w<<<128, 256, 0, stream>>>(W0, W1, W2, W3, wpb);
    gln_fused<<<M / 128, 1024, 131072, stream>>>(x, wpb, b0, b1, b2, b3, out, seg_am);

    scan_bound<<<B * D / 256, 256, 0, stream>>>(seg_am, hidden, seg_state);
    scan_apply<<<(B * D * SEGS) / 256, 256, 0, stream>>>(out, seg_state, last);
}